// Round 4
// baseline (775.842 us; speedup 1.0000x reference)
//
#include <hip/hip_runtime.h>
#include <hip/hip_bf16.h>

#define N_NODES 50000
#define N_EDGES 800000
#define N_GRAPHS 64
#define D 96
#define N_GIN 4
#define BN_EPS 1e-5f
#define PCH 64          // pool chunks per graph (layer-0 pooling)
#define GEMM_GRID 782   // 782 blocks * 4 waves = 3128 waves ~ 3125 strips (1 strip/wave)
#define LP 104          // LDS strip pitch (bf16)
#define ELLCAP 64       // ELL row capacity; deg ~ Poisson(16), P(>=64) ~ 2e-22
#define SENT 50000      // sentinel node index -> phantom zero row in h buffers

// --- two-phase counting sort (dense coalesced writes, LDS atomics only)
#define P1_BLOCKS 256
#define EPB 3125        // N_EDGES / P1_BLOCKS, exact
#define BSH 8
#define BNODES 256      // nodes per bucket = 1 << BSH
#define NBUCK 196       // ceil(N_NODES / BNODES)
#define SPITCH 33       // phase-2 LDS ELL row pitch in u32 (66 u16)

typedef __bf16 bf16;
typedef __bf16 bf16x8 __attribute__((ext_vector_type(8)));
typedef float f32x4 __attribute__((ext_vector_type(4)));
typedef unsigned short u16;
typedef unsigned int u32;
typedef unsigned short u16x8 __attribute__((ext_vector_type(8)));

__device__ inline unsigned enc(float f) {
    unsigned b = __float_as_uint(f);
    return (b & 0x80000000u) ? ~b : (b | 0x80000000u);
}
__device__ inline float dec(unsigned u) {
    return __uint_as_float((u & 0x80000000u) ? (u ^ 0x80000000u) : ~u);
}

// ---------------- fused prolog: cast | weight-prep | zero (block ranges) ----------------
__global__ void k_prolog(const float* __restrict__ h, bf16* __restrict__ hb,
                         bf16* __restrict__ hb1,
                         const float* __restrict__ W1, const float* __restrict__ W2,
                         bf16* __restrict__ wf, float* __restrict__ stats,
                         unsigned* __restrict__ pooledu) {
    int b = blockIdx.x;
    int tid = threadIdx.x;
    if (b < 2344) {
        int e = (b * 256 + tid) * 8;
        if (e >= N_NODES * D) return;
        float4 v0 = *(const float4*)(h + e);
        float4 v1 = *(const float4*)(h + e + 4);
        bf16x8 o;
        o[0] = (bf16)v0.x; o[1] = (bf16)v0.y; o[2] = (bf16)v0.z; o[3] = (bf16)v0.w;
        o[4] = (bf16)v1.x; o[5] = (bf16)v1.y; o[6] = (bf16)v1.z; o[7] = (bf16)v1.w;
        *(bf16x8*)(hb + e) = o;
    } else if (b < 2352) {
        int mat = b - 2344;
        const float* src = (mat < 4) ? (W1 + mat * D * D) : (W2 + (mat - 4) * D * D);
        bf16* dst = wf + mat * D * D;
        for (int p = tid; p < D * D; p += 256) {
            int f = p >> 9;
            int r = p & 511;
            int lane = r >> 3;
            int j = r & 7;
            int q = lane >> 4;
            int m16 = lane & 15;
            int nt = f / 3, ks = f % 3;
            int k = ks * 32 + q * 8 + j;
            int n = nt * 16 + m16;
            dst[p] = (bf16)src[k * D + n];
        }
    } else {
        int t = (b - 2352) * 256 + tid;
        if (t < N_GIN * 2 * 2 * D) stats[t] = 0.0f;
        if (t < 5 * N_GRAPHS * D) pooledu[t] = 0u;
        if (t < D) {                       // phantom zero row for ELL sentinel
            hb[(size_t)SENT * D + t] = (bf16)0.0f;
            hb1[(size_t)SENT * D + t] = (bf16)0.0f;
        }
    }
}

// ---------------- phase 1: per-block counting sort of edges by dst-bucket ------------
__global__ void __launch_bounds__(256) k_part_pool(
        const int* __restrict__ src, const int* __restrict__ dst,
        u32* __restrict__ eo, u16* __restrict__ offs,
        const bf16* __restrict__ hb, unsigned* __restrict__ pooledu) {
    __shared__ u16 sdst[EPB + 3];
    __shared__ u16 ssrc[EPB + 3];
    __shared__ int hist[256];
    __shared__ int incl[256];
    int tid = threadIdx.x;
    if (blockIdx.x < P1_BLOCKS) {
        int e0 = blockIdx.x * EPB;
        hist[tid] = 0;
        __syncthreads();
        for (int i = tid; i < EPB; i += 256) {
            int d = dst[e0 + i];
            sdst[i] = (u16)d;
            ssrc[i] = (u16)src[e0 + i];
            atomicAdd(&hist[d >> BSH], 1);
        }
        __syncthreads();
        int v = hist[tid];
        incl[tid] = v;
        __syncthreads();
        for (int o = 1; o < 256; o <<= 1) {
            int t = (tid >= o) ? incl[tid - o] : 0;
            __syncthreads();
            incl[tid] += t;
            __syncthreads();
        }
        int ex = incl[tid] - v;   // exclusive prefix; tid==NBUCK has v==0 -> total
        if (tid <= NBUCK) offs[tid * P1_BLOCKS + blockIdx.x] = (u16)ex;
        hist[tid] = ex;           // running placement cursor
        __syncthreads();
        for (int i = tid; i < EPB; i += 256) {
            int d = sdst[i];
            int pos = atomicAdd(&hist[d >> BSH], 1);
            eo[e0 + pos] = ((u32)(d & (BNODES - 1)) << 16) | (u32)ssrc[i];
        }
    } else {
        int grp = (blockIdx.x - P1_BLOCKS) * 16 + (tid >> 4);
        int l = tid & 15;
        if (l >= 12) return;
        int g = grp / PCH, c = grp % PCH;
        int gs = (g * N_NODES + N_GRAPHS - 1) / N_GRAPHS;
        int ge = ((g + 1) * N_NODES + N_GRAPHS - 1) / N_GRAPHS;
        int len = ge - gs;
        int rs = gs + (len * c) / PCH;
        int re = gs + (len * (c + 1)) / PCH;
        const bf16x8* __restrict__ base = (const bf16x8*)hb;
        float m[8];
#pragma unroll
        for (int j = 0; j < 8; ++j) m[j] = -3e38f;
        int i = rs;
        for (; i + 2 <= re; i += 2) {
            bf16x8 r0 = base[i * 12 + l];
            bf16x8 r1 = base[(i + 1) * 12 + l];
#pragma unroll
            for (int j = 0; j < 8; ++j) m[j] = fmaxf(m[j], fmaxf((float)r0[j], (float)r1[j]));
        }
        if (i < re) {
            bf16x8 r = base[i * 12 + l];
#pragma unroll
            for (int j = 0; j < 8; ++j) m[j] = fmaxf(m[j], (float)r[j]);
        }
        unsigned* dstp = pooledu + (size_t)g * D + l * 8;
#pragma unroll
        for (int j = 0; j < 8; ++j) atomicMax(&dstp[j], enc(m[j]));
    }
}

// ---------------- phase 2: per-bucket ELL build fully in LDS, coalesced writeback ----
// LDS tile pre-filled with SENT so unused ELL slots point at the phantom zero
// row -> consumer aggregates with degree rounded up, no remainder / no predication.
__global__ void __launch_bounds__(256) k_ell_build(
        const u32* __restrict__ eo, const u16* __restrict__ offs,
        u16* __restrict__ ell, int* __restrict__ cnt) {
    __shared__ u32 sell32[BNODES * SPITCH];   // 33KB, pitch-66 u16 rows
    __shared__ int scnt[BNODES];
    int tid = threadIdx.x;
    int b = blockIdx.x;
    for (int i = tid; i < BNODES * SPITCH; i += 256) sell32[i] = 0xC350C350u; // SENT|SENT
    scnt[tid] = 0;
    __syncthreads();
    int beg = offs[b * P1_BLOCKS + tid];
    int end = offs[(b + 1) * P1_BLOCKS + tid];
    const u32* ep = eo + (size_t)tid * EPB;
    u16* srows = (u16*)sell32;
    for (int i = beg; i < end; ++i) {
        u32 pk = ep[i];
        int dl = pk >> 16;
        int pos = atomicAdd(&scnt[dl], 1);
        if (pos < ELLCAP) srows[dl * (2 * SPITCH) + pos] = (u16)pk;
    }
    __syncthreads();
    int node0 = b << BSH;
    int nn = min(BNODES, N_NODES - node0);
    if (tid < nn) cnt[node0 + tid] = scnt[tid];
    u32* gell = (u32*)(ell + (size_t)node0 * ELLCAP);
    for (int i = tid; i < nn * 32; i += 256) {
        gell[i] = sell32[(i >> 5) * SPITCH + (i & 31)];
    }
}

// ---------------- fused agg + GEMM1: barrier-free per-wave (1 strip/wave), QUAD
// interleaved gather: each q-group's 4 rows in ONE loop -> 32 loads in flight,
// ~3 serial chunk steps. Sentinel slots read the L1-hot phantom zero row.
// launch_bounds(256,3): cap VGPR at 170 so 3 waves/SIMD (grid gives 3.05) hold.
__global__ void __launch_bounds__(256, 3) k_agg_gemm(
        const bf16* __restrict__ prev, const int* __restrict__ cnt,
        const u16* __restrict__ ell, const bf16* __restrict__ Bf,
        const float* __restrict__ bias, bf16* __restrict__ Z,
        float* __restrict__ ssum, float* __restrict__ sssq) {
    __shared__ bf16 sA[4][16 * LP];
    __shared__ float sr1[4][D], sr2[4][D];
    int tid = threadIdx.x;
    int lane = tid & 63, wv = tid >> 6;
    int q = lane >> 4, m16 = lane & 15;
    int strip = blockIdx.x * 4 + wv;

    float psum[6], pssq[6];
#pragma unroll
    for (int f = 0; f < 6; ++f) { psum[f] = 0.0f; pssq[f] = 0.0f; }

    if (strip < 3125) {
        const bf16x8* __restrict__ base = (const bf16x8*)prev;
        int gl = m16;
        if (gl < 12) {
            int n0 = strip * 16 + q;
            int n1 = n0 + 4, n2 = n0 + 8, n3 = n0 + 12;
            float ac0[8], ac1[8], ac2[8], ac3[8];
            bf16x8 s0 = base[n0 * 12 + gl];
            bf16x8 s1 = base[n1 * 12 + gl];
            bf16x8 s2 = base[n2 * 12 + gl];
            bf16x8 s3 = base[n3 * 12 + gl];
#pragma unroll
            for (int j = 0; j < 8; ++j) {
                ac0[j] = (float)s0[j]; ac1[j] = (float)s1[j];
                ac2[j] = (float)s2[j]; ac3[j] = (float)s3[j];
            }
            int d0 = cnt[n0]; if (d0 > ELLCAP) d0 = ELLCAP;
            int d1 = cnt[n1]; if (d1 > ELLCAP) d1 = ELLCAP;
            int d2 = cnt[n2]; if (d2 > ELLCAP) d2 = ELLCAP;
            int d3 = cnt[n3]; if (d3 > ELLCAP) d3 = ELLCAP;
            int mx01 = (d0 > d1) ? d0 : d1;
            int mx23 = (d2 > d3) ? d2 : d3;
            int dgr = (((mx01 > mx23) ? mx01 : mx23) + 7) & ~7;
            const u16* ep0 = ell + (size_t)n0 * ELLCAP;
            const u16* ep1 = ell + (size_t)n1 * ELLCAP;
            const u16* ep2 = ell + (size_t)n2 * ELLCAP;
            const u16* ep3 = ell + (size_t)n3 * ELLCAP;
            for (int e = 0; e < dgr; e += 8) {
                u16x8 i0 = *(const u16x8*)(ep0 + e);
                u16x8 i1 = *(const u16x8*)(ep1 + e);
                u16x8 i2 = *(const u16x8*)(ep2 + e);
                u16x8 i3 = *(const u16x8*)(ep3 + e);
                bf16x8 a0 = base[(int)i0[0] * 12 + gl];
                bf16x8 a1 = base[(int)i0[1] * 12 + gl];
                bf16x8 a2 = base[(int)i0[2] * 12 + gl];
                bf16x8 a3 = base[(int)i0[3] * 12 + gl];
                bf16x8 a4 = base[(int)i0[4] * 12 + gl];
                bf16x8 a5 = base[(int)i0[5] * 12 + gl];
                bf16x8 a6 = base[(int)i0[6] * 12 + gl];
                bf16x8 a7 = base[(int)i0[7] * 12 + gl];
                bf16x8 b0 = base[(int)i1[0] * 12 + gl];
                bf16x8 b1 = base[(int)i1[1] * 12 + gl];
                bf16x8 b2 = base[(int)i1[2] * 12 + gl];
                bf16x8 b3 = base[(int)i1[3] * 12 + gl];
                bf16x8 b4 = base[(int)i1[4] * 12 + gl];
                bf16x8 b5 = base[(int)i1[5] * 12 + gl];
                bf16x8 b6 = base[(int)i1[6] * 12 + gl];
                bf16x8 b7 = base[(int)i1[7] * 12 + gl];
                bf16x8 c0 = base[(int)i2[0] * 12 + gl];
                bf16x8 c1 = base[(int)i2[1] * 12 + gl];
                bf16x8 c2 = base[(int)i2[2] * 12 + gl];
                bf16x8 c3 = base[(int)i2[3] * 12 + gl];
                bf16x8 c4 = base[(int)i2[4] * 12 + gl];
                bf16x8 c5 = base[(int)i2[5] * 12 + gl];
                bf16x8 c6 = base[(int)i2[6] * 12 + gl];
                bf16x8 c7 = base[(int)i2[7] * 12 + gl];
                bf16x8 e0v = base[(int)i3[0] * 12 + gl];
                bf16x8 e1v = base[(int)i3[1] * 12 + gl];
                bf16x8 e2v = base[(int)i3[2] * 12 + gl];
                bf16x8 e3v = base[(int)i3[3] * 12 + gl];
                bf16x8 e4v = base[(int)i3[4] * 12 + gl];
                bf16x8 e5v = base[(int)i3[5] * 12 + gl];
                bf16x8 e6v = base[(int)i3[6] * 12 + gl];
                bf16x8 e7v = base[(int)i3[7] * 12 + gl];
#pragma unroll
                for (int j = 0; j < 8; ++j) {
                    ac0[j] += (float)a0[j] + (float)a1[j] + (float)a2[j] + (float)a3[j]
                            + (float)a4[j] + (float)a5[j] + (float)a6[j] + (float)a7[j];
                    ac1[j] += (float)b0[j] + (float)b1[j] + (float)b2[j] + (float)b3[j]
                            + (float)b4[j] + (float)b5[j] + (float)b6[j] + (float)b7[j];
                    ac2[j] += (float)c0[j] + (float)c1[j] + (float)c2[j] + (float)c3[j]
                            + (float)c4[j] + (float)c5[j] + (float)c6[j] + (float)c7[j];
                    ac3[j] += (float)e0v[j] + (float)e1v[j] + (float)e2v[j] + (float)e3v[j]
                            + (float)e4v[j] + (float)e5v[j] + (float)e6v[j] + (float)e7v[j];
                }
            }
            bf16x8 o0, o1, o2, o3;
#pragma unroll
            for (int j = 0; j < 8; ++j) {
                o0[j] = (bf16)ac0[j]; o1[j] = (bf16)ac1[j];
                o2[j] = (bf16)ac2[j]; o3[j] = (bf16)ac3[j];
            }
            *(bf16x8*)&sA[wv][q * LP + gl * 8] = o0;
            *(bf16x8*)&sA[wv][(4 + q) * LP + gl * 8] = o1;
            *(bf16x8*)&sA[wv][(8 + q) * LP + gl * 8] = o2;
            *(bf16x8*)&sA[wv][(12 + q) * LP + gl * 8] = o3;
        }
        __asm__ volatile("s_waitcnt lgkmcnt(0)" ::: "memory");

        bf16x8 bfr[18];
#pragma unroll
        for (int f = 0; f < 18; ++f) bfr[f] = *(const bf16x8*)(Bf + (f * 64 + lane) * 8);

        bf16x8 a0 = *(const bf16x8*)&sA[wv][m16 * LP + q * 8];
        bf16x8 a1 = *(const bf16x8*)&sA[wv][m16 * LP + 32 + q * 8];
        bf16x8 a2 = *(const bf16x8*)&sA[wv][m16 * LP + 64 + q * 8];

#pragma unroll
        for (int f = 0; f < 6; ++f) {
            f32x4 acc = {0.0f, 0.0f, 0.0f, 0.0f};
            acc = __builtin_amdgcn_mfma_f32_16x16x32_bf16(a0, bfr[f * 3 + 0], acc, 0, 0, 0);
            acc = __builtin_amdgcn_mfma_f32_16x16x32_bf16(a1, bfr[f * 3 + 1], acc, 0, 0, 0);
            acc = __builtin_amdgcn_mfma_f32_16x16x32_bf16(a2, bfr[f * 3 + 2], acc, 0, 0, 0);
            int col = f * 16 + m16;
            float bvf = bias[col];
            bf16* zp = Z + (size_t)(strip * 16 + q * 4) * D + col;
#pragma unroll
            for (int i = 0; i < 4; ++i) {
                float v = acc[i] + bvf;
                zp[(size_t)i * D] = (bf16)v;
                psum[f] += v;
                pssq[f] += v * v;
            }
        }
    }
#pragma unroll
    for (int f = 0; f < 6; ++f) {
        float r = psum[f];
        r += __shfl_xor(r, 16);
        r += __shfl_xor(r, 32);
        float r2 = pssq[f];
        r2 += __shfl_xor(r2, 16);
        r2 += __shfl_xor(r2, 32);
        if (lane < 16) {
            sr1[wv][f * 16 + lane] = r;
            sr2[wv][f * 16 + lane] = r2;
        }
    }
    __syncthreads();
    int t = wv * 64 + lane;
    if (t < D) {
        atomicAdd(&ssum[t], sr1[0][t] + sr1[1][t] + sr1[2][t] + sr1[3][t]);
    } else if (t < 2 * D) {
        int u = t - D;
        atomicAdd(&sssq[u], sr2[0][u] + sr2[1][u] + sr2[2][u] + sr2[3][u]);
    }
}

// ---------------- elementwise transform: h' = prelu(bn2(z2)) (once per node) --------
__global__ void k_transform(const bf16* __restrict__ Z, const float* __restrict__ st,
                            const float* __restrict__ gamma, const float* __restrict__ beta,
                            const float* __restrict__ pa, bf16* __restrict__ O) {
    __shared__ float cs[D], ct[D];
    int t = threadIdx.x;
    if (t < D) {
        float m = st[t] * (1.0f / N_NODES);
        float v = st[D + t] * (1.0f / N_NODES) - m * m;
        float inv = rsqrtf(v + BN_EPS);
        float sc = gamma[t] * inv;
        cs[t] = sc;
        ct[t] = beta[t] - m * sc;
    }
    __syncthreads();
    int e = (blockIdx.x * 256 + t) * 8;
    if (e >= N_NODES * D) return;
    float alpha = pa[0];
    int c = e % D;
    bf16x8 z = *(const bf16x8*)(Z + e);
    bf16x8 o;
#pragma unroll
    for (int j = 0; j < 8; ++j) {
        float v = (float)z[j] * cs[c + j] + ct[c + j];
        o[j] = (bf16)(v >= 0.0f ? v : alpha * v);
    }
    *(bf16x8*)(O + e) = o;
}

// ---------------- GEMM2 fused: BN1 finalize + affine + ReLU on A-load,
// Z2 raw stored; BN2 stats; RAW per-graph col-max via LDS pre-reduction ----------------
__global__ void __launch_bounds__(256) k_gemm_fused(
        const bf16* __restrict__ A, const bf16* __restrict__ Bf,
        const float* __restrict__ st, const float* __restrict__ gamma,
        const float* __restrict__ beta, const float* __restrict__ bias,
        bf16* __restrict__ Z, float* __restrict__ ssum, float* __restrict__ sssq,
        unsigned* __restrict__ poolu) {
    __shared__ float cs[D], ct[D];
    __shared__ float sr1[4][D];
    __shared__ float sr2[4][D];
    __shared__ unsigned pmax[2 * D];
    int tid = threadIdx.x;
    if (tid < D) {
        float m = st[tid] * (1.0f / N_NODES);
        float v = st[D + tid] * (1.0f / N_NODES) - m * m;
        float inv = rsqrtf(v + BN_EPS);
        float sc = gamma[tid] * inv;
        cs[tid] = sc;
        ct[tid] = beta[tid] - m * sc;
    }
    if (tid < 2 * D) pmax[tid] = 0u;
    __syncthreads();

    int lane = tid & 63;
    int wv = tid >> 6;
    int w = (blockIdx.x * blockDim.x + tid) >> 6;
    int nw = (gridDim.x * blockDim.x) >> 6;
    int q = lane >> 4, m16 = lane & 15;
    int g0 = (int)(((long long)blockIdx.x * 64) * N_GRAPHS / N_NODES);

    float as_[3][8], at_[3][8];
#pragma unroll
    for (int ks = 0; ks < 3; ++ks)
#pragma unroll
        for (int j = 0; j < 8; ++j) {
            as_[ks][j] = cs[ks * 32 + q * 8 + j];
            at_[ks][j] = ct[ks * 32 + q * 8 + j];
        }

    bf16x8 bfr[18];
#pragma unroll
    for (int f = 0; f < 18; ++f) bfr[f] = *(const bf16x8*)(Bf + (f * 64 + lane) * 8);
    float bv[6];
#pragma unroll
    for (int f = 0; f < 6; ++f) bv[f] = bias[f * 16 + m16];
    float psum[6], pssq[6];
#pragma unroll
    for (int f = 0; f < 6; ++f) { psum[f] = 0.0f; pssq[f] = 0.0f; }

    const int NSTRIP = N_NODES / 16;
    for (int s = w; s < NSTRIP; s += nw) {
        const bf16* arow = A + (size_t)(s * 16 + m16) * D;
        bf16x8 z0 = *(const bf16x8*)(arow + q * 8);
        bf16x8 z1 = *(const bf16x8*)(arow + 32 + q * 8);
        bf16x8 z2 = *(const bf16x8*)(arow + 64 + q * 8);
        bf16x8 a0, a1, a2;
#pragma unroll
        for (int j = 0; j < 8; ++j) {
            a0[j] = (bf16)fmaxf(0.0f, (float)z0[j] * as_[0][j] + at_[0][j]);
            a1[j] = (bf16)fmaxf(0.0f, (float)z1[j] * as_[1][j] + at_[1][j]);
            a2[j] = (bf16)fmaxf(0.0f, (float)z2[j] * as_[2][j] + at_[2][j]);
        }
#pragma unroll
        for (int f = 0; f < 6; ++f) {
            f32x4 acc = {0.0f, 0.0f, 0.0f, 0.0f};
            acc = __builtin_amdgcn_mfma_f32_16x16x32_bf16(a0, bfr[f * 3 + 0], acc, 0, 0, 0);
            acc = __builtin_amdgcn_mfma_f32_16x16x32_bf16(a1, bfr[f * 3 + 1], acc, 0, 0, 0);
            acc = __builtin_amdgcn_mfma_f32_16x16x32_bf16(a2, bfr[f * 3 + 2], acc, 0, 0, 0);
            int col = f * 16 + m16;
            bf16* zp = Z + (size_t)(s * 16 + q * 4) * D + col;
#pragma unroll
            for (int i = 0; i < 4; ++i) {
                float v = acc[i] + bv[f];
                zp[(size_t)i * D] = (bf16)v;
                psum[f] += v;
                pssq[f] += v * v;
                int row = s * 16 + q * 4 + i;
                int g = (int)(((unsigned)row * 64u) / 50000u);
                int slot = g - g0;
                if (slot >= 0 && slot < 2)
                    atomicMax(&pmax[slot * D + col], enc(v));   // LDS atomic
            }
        }
    }
#pragma unroll
    for (int f = 0; f < 6; ++f) {
        float r = psum[f];
        r += __shfl_xor(r, 16);
        r += __shfl_xor(r, 32);
        float r2 = pssq[f];
        r2 += __shfl_xor(r2, 16);
        r2 += __shfl_xor(r2, 32);
        if (lane < 16) {
            sr1[wv][f * 16 + lane] = r;
            sr2[wv][f * 16 + lane] = r2;
        }
    }
    __syncthreads();
    int t = wv * 64 + lane;
    if (t < D) {
        atomicAdd(&ssum[t], sr1[0][t] + sr1[1][t] + sr1[2][t] + sr1[3][t]);
    } else if (t < 2 * D) {
        int u = t - D;
        atomicAdd(&sssq[u], sr2[0][u] + sr2[1][u] + sr2[2][u] + sr2[3][u]);
    }
    if (t < 2 * D) {
        int sl = t / D, c = t % D;
        int gg = g0 + sl;
        if (gg < N_GRAPHS && pmax[t] != 0u)
            atomicMax(&poolu[gg * D + c], pmax[t]);
    }
}

// ---------------- head GEMMs: decode raw pooled max, apply prelu(bn2(.)) for l>=1 ----
__global__ void k_heads(const unsigned* __restrict__ pooledu, const float* __restrict__ stats,
                        const float* __restrict__ bng, const float* __restrict__ bnb,
                        const float* __restrict__ pa, const float* __restrict__ W,
                        const float* __restrict__ B, float* __restrict__ out) {
    __shared__ float pv[D];
    int b = blockIdx.x;
    int l = b >> 6;
    int g = b & 63;
    int d = threadIdx.x;
    if (d < D) {
        float m = dec(pooledu[(size_t)(l * N_GRAPHS + g) * D + d]);
        if (l > 0) {
            int gl = l - 1;
            const float* st = stats + (gl * 2 + 1) * 2 * D;
            float mean = st[d] * (1.0f / N_NODES);
            float var = st[D + d] * (1.0f / N_NODES) - mean * mean;
            float inv = rsqrtf(var + BN_EPS);
            float s = bng[gl * D + d] * inv;
            float t = bnb[gl * D + d] - mean * s;
            float v = m * s + t;
            m = (v >= 0.0f) ? v : pa[0] * v;
        }
        pv[d] = m;
    }
    __syncthreads();
    if (d >= D) return;
    const float* w = W + (size_t)l * D * D;
    float acc = B[l * D + d];
    for (int k = 0; k < D; ++k) acc += pv[k] * w[k * D + d];
    out[g * (5 * D) + d * 5 + l] = acc;
}

extern "C" void kernel_launch(void* const* d_in, const int* in_sizes, int n_in,
                              void* d_out, int out_size, void* d_ws, size_t ws_size,
                              hipStream_t stream) {
    const float* h     = (const float*)d_in[0];
    const float* gW1   = (const float*)d_in[1];
    const float* gb1   = (const float*)d_in[2];
    const float* bn1g  = (const float*)d_in[3];
    const float* bn1b  = (const float*)d_in[4];
    const float* gW2   = (const float*)d_in[5];
    const float* gb2   = (const float*)d_in[6];
    const float* bng   = (const float*)d_in[7];
    const float* bnb   = (const float*)d_in[8];
    const float* prelu = (const float*)d_in[9];
    const float* linW  = (const float*)d_in[10];
    const float* linb  = (const float*)d_in[11];
    const int*   srcv  = (const int*)d_in[12];
    const int*   dstv  = (const int*)d_in[13];
    float* out = (float*)d_out;

    char* base = (char*)d_ws;
    size_t off = 0;
    auto carve = [&](size_t bytes) -> void* {
        void* p = base + off;
        off += (bytes + 255) & ~(size_t)255;
        return p;
    };
    const size_t HB = (size_t)N_NODES * D;
    bf16* hb0   = (bf16*)carve((HB + D) * 2);   // h'_0 + phantom zero row (SENT)
    bf16* hb1   = (bf16*)carve((HB + D) * 2);   // h'_l for l>=1 + phantom zero row
    bf16* zb    = (bf16*)carve(HB * 2);         // z1
    bf16* ab    = (bf16*)carve(HB * 2);         // raw z2
    bf16* wf    = (bf16*)carve(8 * D * D * 2);
    float* stats = (float*)carve(N_GIN * 2 * 2 * D * 4);
    int* cnt    = (int*)carve((size_t)N_NODES * 4);              // compact degrees
    u16* ell    = (u16*)carve((size_t)N_NODES * ELLCAP * 2);     // ELL adjacency
    u32* eo     = (u32*)carve((size_t)N_EDGES * 4);              // bucket-sorted edges
    u16* offs   = (u16*)carve((size_t)(NBUCK + 1) * P1_BLOCKS * 2);
    unsigned* pooledu = (unsigned*)carve(5 * N_GRAPHS * D * 4);

    k_prolog<<<2472, 256, 0, stream>>>(h, hb0, hb1, gW1, gW2, wf, stats, pooledu);
    k_part_pool<<<P1_BLOCKS + N_GRAPHS * PCH / 16, 256, 0, stream>>>(
        srcv, dstv, eo, offs, hb0, pooledu);
    k_ell_build<<<NBUCK, 256, 0, stream>>>(eo, offs, ell, cnt);

    const bf16* prev = hb0;
    for (int l = 0; l < N_GIN; ++l) {
        float* st1 = stats + (l * 2 + 0) * 2 * D;
        float* st2 = stats + (l * 2 + 1) * 2 * D;
        if (l > 0) {
            float* stp = stats + ((l - 1) * 2 + 1) * 2 * D;
            k_transform<<<2344, 256, 0, stream>>>(ab, stp, bng + (l - 1) * D,
                                                  bnb + (l - 1) * D, prelu, hb1);
            prev = hb1;
        }
        k_agg_gemm<<<GEMM_GRID, 256, 0, stream>>>(prev, cnt, ell, wf + l * D * D,
                                                  gb1 + l * D, zb, st1, st1 + D);
        k_gemm_fused<<<GEMM_GRID, 256, 0, stream>>>(zb, wf + (4 + l) * D * D, st1,
                                                    bn1g + l * D, bn1b + l * D,
                                                    gb2 + l * D, ab, st2, st2 + D,
                                                    pooledu + (size_t)(l + 1) * N_GRAPHS * D);
    }
    k_heads<<<5 * N_GRAPHS, 128, 0, stream>>>(pooledu, stats, bng, bnb, prelu,
                                              linW, linb, out);
}

// Round 5
// 429.522 us; speedup vs baseline: 1.8063x; 1.8063x over previous
//
#include <hip/hip_runtime.h>
#include <hip/hip_bf16.h>

#define N_NODES 50000
#define N_EDGES 800000
#define N_GRAPHS 64
#define D 96
#define N_GIN 4
#define BN_EPS 1e-5f
#define PCH 64          // pool chunks per graph (layer-0 pooling)
#define GEMM_GRID 782   // 782 blocks * 4 waves = 3128 waves ~ 3125 strips (1 strip/wave)
#define LP 104          // LDS strip pitch (bf16)
#define ELLCAP 64       // ELL row capacity; deg ~ Poisson(16), P(>=64) ~ 2e-22
#define SENT 50000      // sentinel node index -> phantom zero row in h buffers

// --- two-phase counting sort (dense coalesced writes, LDS atomics only)
#define P1_BLOCKS 256
#define EPB 3125        // N_EDGES / P1_BLOCKS, exact
#define BSH 8
#define BNODES 256      // nodes per bucket = 1 << BSH
#define NBUCK 196       // ceil(N_NODES / BNODES)
#define SPITCH 33       // phase-2 LDS ELL row pitch in u32 (66 u16)

typedef __bf16 bf16;
typedef __bf16 bf16x8 __attribute__((ext_vector_type(8)));
typedef float f32x4 __attribute__((ext_vector_type(4)));
typedef unsigned short u16;
typedef unsigned int u32;
typedef unsigned short u16x8 __attribute__((ext_vector_type(8)));

__device__ inline unsigned enc(float f) {
    unsigned b = __float_as_uint(f);
    return (b & 0x80000000u) ? ~b : (b | 0x80000000u);
}
__device__ inline float dec(unsigned u) {
    return __uint_as_float((u & 0x80000000u) ? (u ^ 0x80000000u) : ~u);
}

// ---------------- fused prolog: cast | weight-prep | zero (block ranges) ----------------
__global__ void k_prolog(const float* __restrict__ h, bf16* __restrict__ hb,
                         bf16* __restrict__ hb1,
                         const float* __restrict__ W1, const float* __restrict__ W2,
                         bf16* __restrict__ wf, float* __restrict__ stats,
                         unsigned* __restrict__ pooledu) {
    int b = blockIdx.x;
    int tid = threadIdx.x;
    if (b < 2344) {
        int e = (b * 256 + tid) * 8;
        if (e >= N_NODES * D) return;
        float4 v0 = *(const float4*)(h + e);
        float4 v1 = *(const float4*)(h + e + 4);
        bf16x8 o;
        o[0] = (bf16)v0.x; o[1] = (bf16)v0.y; o[2] = (bf16)v0.z; o[3] = (bf16)v0.w;
        o[4] = (bf16)v1.x; o[5] = (bf16)v1.y; o[6] = (bf16)v1.z; o[7] = (bf16)v1.w;
        *(bf16x8*)(hb + e) = o;
    } else if (b < 2352) {
        int mat = b - 2344;
        const float* src = (mat < 4) ? (W1 + mat * D * D) : (W2 + (mat - 4) * D * D);
        bf16* dst = wf + mat * D * D;
        for (int p = tid; p < D * D; p += 256) {
            int f = p >> 9;
            int r = p & 511;
            int lane = r >> 3;
            int j = r & 7;
            int q = lane >> 4;
            int m16 = lane & 15;
            int nt = f / 3, ks = f % 3;
            int k = ks * 32 + q * 8 + j;
            int n = nt * 16 + m16;
            dst[p] = (bf16)src[k * D + n];
        }
    } else {
        int t = (b - 2352) * 256 + tid;
        if (t < N_GIN * 2 * 2 * D) stats[t] = 0.0f;
        if (t < 5 * N_GRAPHS * D) pooledu[t] = 0u;
        if (t < D) {                       // phantom zero row for ELL sentinel
            hb[(size_t)SENT * D + t] = (bf16)0.0f;
            hb1[(size_t)SENT * D + t] = (bf16)0.0f;
        }
    }
}

// ---------------- phase 1: per-block counting sort of edges by dst-bucket ------------
__global__ void __launch_bounds__(256) k_part_pool(
        const int* __restrict__ src, const int* __restrict__ dst,
        u32* __restrict__ eo, u16* __restrict__ offs,
        const bf16* __restrict__ hb, unsigned* __restrict__ pooledu) {
    __shared__ u16 sdst[EPB + 3];
    __shared__ u16 ssrc[EPB + 3];
    __shared__ int hist[256];
    __shared__ int incl[256];
    int tid = threadIdx.x;
    if (blockIdx.x < P1_BLOCKS) {
        int e0 = blockIdx.x * EPB;
        hist[tid] = 0;
        __syncthreads();
        for (int i = tid; i < EPB; i += 256) {
            int d = dst[e0 + i];
            sdst[i] = (u16)d;
            ssrc[i] = (u16)src[e0 + i];
            atomicAdd(&hist[d >> BSH], 1);
        }
        __syncthreads();
        int v = hist[tid];
        incl[tid] = v;
        __syncthreads();
        for (int o = 1; o < 256; o <<= 1) {
            int t = (tid >= o) ? incl[tid - o] : 0;
            __syncthreads();
            incl[tid] += t;
            __syncthreads();
        }
        int ex = incl[tid] - v;   // exclusive prefix; tid==NBUCK has v==0 -> total
        if (tid <= NBUCK) offs[tid * P1_BLOCKS + blockIdx.x] = (u16)ex;
        hist[tid] = ex;           // running placement cursor
        __syncthreads();
        for (int i = tid; i < EPB; i += 256) {
            int d = sdst[i];
            int pos = atomicAdd(&hist[d >> BSH], 1);
            eo[e0 + pos] = ((u32)(d & (BNODES - 1)) << 16) | (u32)ssrc[i];
        }
    } else {
        int grp = (blockIdx.x - P1_BLOCKS) * 16 + (tid >> 4);
        int l = tid & 15;
        if (l >= 12) return;
        int g = grp / PCH, c = grp % PCH;
        int gs = (g * N_NODES + N_GRAPHS - 1) / N_GRAPHS;
        int ge = ((g + 1) * N_NODES + N_GRAPHS - 1) / N_GRAPHS;
        int len = ge - gs;
        int rs = gs + (len * c) / PCH;
        int re = gs + (len * (c + 1)) / PCH;
        const bf16x8* __restrict__ base = (const bf16x8*)hb;
        float m[8];
#pragma unroll
        for (int j = 0; j < 8; ++j) m[j] = -3e38f;
        int i = rs;
        for (; i + 2 <= re; i += 2) {
            bf16x8 r0 = base[i * 12 + l];
            bf16x8 r1 = base[(i + 1) * 12 + l];
#pragma unroll
            for (int j = 0; j < 8; ++j) m[j] = fmaxf(m[j], fmaxf((float)r0[j], (float)r1[j]));
        }
        if (i < re) {
            bf16x8 r = base[i * 12 + l];
#pragma unroll
            for (int j = 0; j < 8; ++j) m[j] = fmaxf(m[j], (float)r[j]);
        }
        unsigned* dstp = pooledu + (size_t)g * D + l * 8;
#pragma unroll
        for (int j = 0; j < 8; ++j) atomicMax(&dstp[j], enc(m[j]));
    }
}

// ---------------- phase 2: per-bucket ELL build fully in LDS, coalesced writeback ----
// LDS tile pre-filled with SENT so unused ELL slots point at the phantom zero
// row -> consumer aggregates with degree rounded up, no remainder / no predication.
__global__ void __launch_bounds__(256) k_ell_build(
        const u32* __restrict__ eo, const u16* __restrict__ offs,
        u16* __restrict__ ell, int* __restrict__ cnt) {
    __shared__ u32 sell32[BNODES * SPITCH];   // 33KB, pitch-66 u16 rows
    __shared__ int scnt[BNODES];
    int tid = threadIdx.x;
    int b = blockIdx.x;
    for (int i = tid; i < BNODES * SPITCH; i += 256) sell32[i] = 0xC350C350u; // SENT|SENT
    scnt[tid] = 0;
    __syncthreads();
    int beg = offs[b * P1_BLOCKS + tid];
    int end = offs[(b + 1) * P1_BLOCKS + tid];
    const u32* ep = eo + (size_t)tid * EPB;
    u16* srows = (u16*)sell32;
    for (int i = beg; i < end; ++i) {
        u32 pk = ep[i];
        int dl = pk >> 16;
        int pos = atomicAdd(&scnt[dl], 1);
        if (pos < ELLCAP) srows[dl * (2 * SPITCH) + pos] = (u16)pk;
    }
    __syncthreads();
    int node0 = b << BSH;
    int nn = min(BNODES, N_NODES - node0);
    if (tid < nn) cnt[node0 + tid] = scnt[tid];
    u32* gell = (u32*)(ell + (size_t)node0 * ELLCAP);
    for (int i = tid; i < nn * 32; i += 256) {
        gell[i] = sell32[(i >> 5) * SPITCH + (i & 31)];
    }
}

// ---------------- fused agg + GEMM1: barrier-free per-wave (1 strip/wave), node-PAIR
// interleaved gather (16 data loads in flight) + index DOUBLE-BUFFER: next chunk's
// u16x8 index vectors are prefetched unconditionally each iteration, removing the
// index-load latency from every serial chunk step. Prefetched values past dgr are
// never dereferenced (<=16B over-read past the last ELL row lands in the eo carve).
// R4 lesson: quad-interleave (32 data temps) spills at any usable occupancy cap.
__global__ void __launch_bounds__(256) k_agg_gemm(
        const bf16* __restrict__ prev, const int* __restrict__ cnt,
        const u16* __restrict__ ell, const bf16* __restrict__ Bf,
        const float* __restrict__ bias, bf16* __restrict__ Z,
        float* __restrict__ ssum, float* __restrict__ sssq) {
    __shared__ bf16 sA[4][16 * LP];
    __shared__ float sr1[4][D], sr2[4][D];
    int tid = threadIdx.x;
    int lane = tid & 63, wv = tid >> 6;
    int q = lane >> 4, m16 = lane & 15;
    int strip = blockIdx.x * 4 + wv;

    float psum[6], pssq[6];
#pragma unroll
    for (int f = 0; f < 6; ++f) { psum[f] = 0.0f; pssq[f] = 0.0f; }

    if (strip < 3125) {
        const bf16x8* __restrict__ base = (const bf16x8*)prev;
        int gl = m16;
        if (gl < 12) {
#pragma unroll 1
            for (int rp = 0; rp < 2; ++rp) {
                // rows rp*8+q and rp*8+4+q of this strip (pair interleave)
                int nA = strip * 16 + rp * 8 + q;
                int nB = nA + 4;
                float accA[8], accB[8];
                bf16x8 selfA = base[nA * 12 + gl];
                bf16x8 selfB = base[nB * 12 + gl];
#pragma unroll
                for (int j = 0; j < 8; ++j) { accA[j] = (float)selfA[j]; accB[j] = (float)selfB[j]; }
                int dgA = cnt[nA]; if (dgA > ELLCAP) dgA = ELLCAP;
                int dgB = cnt[nB]; if (dgB > ELLCAP) dgB = ELLCAP;
                int dgr = (((dgA > dgB) ? dgA : dgB) + 7) & ~7;
                const u16* epA = ell + (size_t)nA * ELLCAP;
                const u16* epB = ell + (size_t)nB * ELLCAP;
                u16x8 ivA = *(const u16x8*)(epA);
                u16x8 ivB = *(const u16x8*)(epB);
                for (int e = 0; e < dgr; e += 8) {
                    // prefetch next chunk's indices (unused past dgr; never dereferenced)
                    u16x8 nxA = *(const u16x8*)(epA + e + 8);
                    u16x8 nxB = *(const u16x8*)(epB + e + 8);
                    bf16x8 a0 = base[(int)ivA[0] * 12 + gl];
                    bf16x8 a1 = base[(int)ivA[1] * 12 + gl];
                    bf16x8 a2 = base[(int)ivA[2] * 12 + gl];
                    bf16x8 a3 = base[(int)ivA[3] * 12 + gl];
                    bf16x8 a4 = base[(int)ivA[4] * 12 + gl];
                    bf16x8 a5 = base[(int)ivA[5] * 12 + gl];
                    bf16x8 a6 = base[(int)ivA[6] * 12 + gl];
                    bf16x8 a7 = base[(int)ivA[7] * 12 + gl];
                    bf16x8 b0 = base[(int)ivB[0] * 12 + gl];
                    bf16x8 b1 = base[(int)ivB[1] * 12 + gl];
                    bf16x8 b2 = base[(int)ivB[2] * 12 + gl];
                    bf16x8 b3 = base[(int)ivB[3] * 12 + gl];
                    bf16x8 b4 = base[(int)ivB[4] * 12 + gl];
                    bf16x8 b5 = base[(int)ivB[5] * 12 + gl];
                    bf16x8 b6 = base[(int)ivB[6] * 12 + gl];
                    bf16x8 b7 = base[(int)ivB[7] * 12 + gl];
#pragma unroll
                    for (int j = 0; j < 8; ++j) {
                        accA[j] += (float)a0[j] + (float)a1[j] + (float)a2[j] + (float)a3[j]
                                 + (float)a4[j] + (float)a5[j] + (float)a6[j] + (float)a7[j];
                        accB[j] += (float)b0[j] + (float)b1[j] + (float)b2[j] + (float)b3[j]
                                 + (float)b4[j] + (float)b5[j] + (float)b6[j] + (float)b7[j];
                    }
                    ivA = nxA;
                    ivB = nxB;
                }
                bf16x8 oA, oB;
#pragma unroll
                for (int j = 0; j < 8; ++j) { oA[j] = (bf16)accA[j]; oB[j] = (bf16)accB[j]; }
                *(bf16x8*)&sA[wv][(rp * 8 + q) * LP + gl * 8] = oA;
                *(bf16x8*)&sA[wv][(rp * 8 + 4 + q) * LP + gl * 8] = oB;
            }
        }
        __asm__ volatile("s_waitcnt lgkmcnt(0)" ::: "memory");

        bf16x8 bfr[18];
#pragma unroll
        for (int f = 0; f < 18; ++f) bfr[f] = *(const bf16x8*)(Bf + (f * 64 + lane) * 8);

        bf16x8 a0 = *(const bf16x8*)&sA[wv][m16 * LP + q * 8];
        bf16x8 a1 = *(const bf16x8*)&sA[wv][m16 * LP + 32 + q * 8];
        bf16x8 a2 = *(const bf16x8*)&sA[wv][m16 * LP + 64 + q * 8];

#pragma unroll
        for (int f = 0; f < 6; ++f) {
            f32x4 acc = {0.0f, 0.0f, 0.0f, 0.0f};
            acc = __builtin_amdgcn_mfma_f32_16x16x32_bf16(a0, bfr[f * 3 + 0], acc, 0, 0, 0);
            acc = __builtin_amdgcn_mfma_f32_16x16x32_bf16(a1, bfr[f * 3 + 1], acc, 0, 0, 0);
            acc = __builtin_amdgcn_mfma_f32_16x16x32_bf16(a2, bfr[f * 3 + 2], acc, 0, 0, 0);
            int col = f * 16 + m16;
            float bvf = bias[col];
            bf16* zp = Z + (size_t)(strip * 16 + q * 4) * D + col;
#pragma unroll
            for (int i = 0; i < 4; ++i) {
                float v = acc[i] + bvf;
                zp[(size_t)i * D] = (bf16)v;
                psum[f] += v;
                pssq[f] += v * v;
            }
        }
    }
#pragma unroll
    for (int f = 0; f < 6; ++f) {
        float r = psum[f];
        r += __shfl_xor(r, 16);
        r += __shfl_xor(r, 32);
        float r2 = pssq[f];
        r2 += __shfl_xor(r2, 16);
        r2 += __shfl_xor(r2, 32);
        if (lane < 16) {
            sr1[wv][f * 16 + lane] = r;
            sr2[wv][f * 16 + lane] = r2;
        }
    }
    __syncthreads();
    int t = wv * 64 + lane;
    if (t < D) {
        atomicAdd(&ssum[t], sr1[0][t] + sr1[1][t] + sr1[2][t] + sr1[3][t]);
    } else if (t < 2 * D) {
        int u = t - D;
        atomicAdd(&sssq[u], sr2[0][u] + sr2[1][u] + sr2[2][u] + sr2[3][u]);
    }
}

// ---------------- elementwise transform: h' = prelu(bn2(z2)) (once per node) --------
__global__ void k_transform(const bf16* __restrict__ Z, const float* __restrict__ st,
                            const float* __restrict__ gamma, const float* __restrict__ beta,
                            const float* __restrict__ pa, bf16* __restrict__ O) {
    __shared__ float cs[D], ct[D];
    int t = threadIdx.x;
    if (t < D) {
        float m = st[t] * (1.0f / N_NODES);
        float v = st[D + t] * (1.0f / N_NODES) - m * m;
        float inv = rsqrtf(v + BN_EPS);
        float sc = gamma[t] * inv;
        cs[t] = sc;
        ct[t] = beta[t] - m * sc;
    }
    __syncthreads();
    int e = (blockIdx.x * 256 + t) * 8;
    if (e >= N_NODES * D) return;
    float alpha = pa[0];
    int c = e % D;
    bf16x8 z = *(const bf16x8*)(Z + e);
    bf16x8 o;
#pragma unroll
    for (int j = 0; j < 8; ++j) {
        float v = (float)z[j] * cs[c + j] + ct[c + j];
        o[j] = (bf16)(v >= 0.0f ? v : alpha * v);
    }
    *(bf16x8*)(O + e) = o;
}

// ---------------- GEMM2 fused: BN1 finalize + affine + ReLU on A-load,
// Z2 raw stored; BN2 stats; RAW per-graph col-max via LDS pre-reduction ----------------
__global__ void __launch_bounds__(256) k_gemm_fused(
        const bf16* __restrict__ A, const bf16* __restrict__ Bf,
        const float* __restrict__ st, const float* __restrict__ gamma,
        const float* __restrict__ beta, const float* __restrict__ bias,
        bf16* __restrict__ Z, float* __restrict__ ssum, float* __restrict__ sssq,
        unsigned* __restrict__ poolu) {
    __shared__ float cs[D], ct[D];
    __shared__ float sr1[4][D];
    __shared__ float sr2[4][D];
    __shared__ unsigned pmax[2 * D];
    int tid = threadIdx.x;
    if (tid < D) {
        float m = st[tid] * (1.0f / N_NODES);
        float v = st[D + tid] * (1.0f / N_NODES) - m * m;
        float inv = rsqrtf(v + BN_EPS);
        float sc = gamma[tid] * inv;
        cs[tid] = sc;
        ct[tid] = beta[tid] - m * sc;
    }
    if (tid < 2 * D) pmax[tid] = 0u;
    __syncthreads();

    int lane = tid & 63;
    int wv = tid >> 6;
    int w = (blockIdx.x * blockDim.x + tid) >> 6;
    int nw = (gridDim.x * blockDim.x) >> 6;
    int q = lane >> 4, m16 = lane & 15;
    int g0 = (int)(((long long)blockIdx.x * 64) * N_GRAPHS / N_NODES);

    float as_[3][8], at_[3][8];
#pragma unroll
    for (int ks = 0; ks < 3; ++ks)
#pragma unroll
        for (int j = 0; j < 8; ++j) {
            as_[ks][j] = cs[ks * 32 + q * 8 + j];
            at_[ks][j] = ct[ks * 32 + q * 8 + j];
        }

    bf16x8 bfr[18];
#pragma unroll
    for (int f = 0; f < 18; ++f) bfr[f] = *(const bf16x8*)(Bf + (f * 64 + lane) * 8);
    float bv[6];
#pragma unroll
    for (int f = 0; f < 6; ++f) bv[f] = bias[f * 16 + m16];
    float psum[6], pssq[6];
#pragma unroll
    for (int f = 0; f < 6; ++f) { psum[f] = 0.0f; pssq[f] = 0.0f; }

    const int NSTRIP = N_NODES / 16;
    for (int s = w; s < NSTRIP; s += nw) {
        const bf16* arow = A + (size_t)(s * 16 + m16) * D;
        bf16x8 z0 = *(const bf16x8*)(arow + q * 8);
        bf16x8 z1 = *(const bf16x8*)(arow + 32 + q * 8);
        bf16x8 z2 = *(const bf16x8*)(arow + 64 + q * 8);
        bf16x8 a0, a1, a2;
#pragma unroll
        for (int j = 0; j < 8; ++j) {
            a0[j] = (bf16)fmaxf(0.0f, (float)z0[j] * as_[0][j] + at_[0][j]);
            a1[j] = (bf16)fmaxf(0.0f, (float)z1[j] * as_[1][j] + at_[1][j]);
            a2[j] = (bf16)fmaxf(0.0f, (float)z2[j] * as_[2][j] + at_[2][j]);
        }
#pragma unroll
        for (int f = 0; f < 6; ++f) {
            f32x4 acc = {0.0f, 0.0f, 0.0f, 0.0f};
            acc = __builtin_amdgcn_mfma_f32_16x16x32_bf16(a0, bfr[f * 3 + 0], acc, 0, 0, 0);
            acc = __builtin_amdgcn_mfma_f32_16x16x32_bf16(a1, bfr[f * 3 + 1], acc, 0, 0, 0);
            acc = __builtin_amdgcn_mfma_f32_16x16x32_bf16(a2, bfr[f * 3 + 2], acc, 0, 0, 0);
            int col = f * 16 + m16;
            bf16* zp = Z + (size_t)(s * 16 + q * 4) * D + col;
#pragma unroll
            for (int i = 0; i < 4; ++i) {
                float v = acc[i] + bv[f];
                zp[(size_t)i * D] = (bf16)v;
                psum[f] += v;
                pssq[f] += v * v;
                int row = s * 16 + q * 4 + i;
                int g = (int)(((unsigned)row * 64u) / 50000u);
                int slot = g - g0;
                if (slot >= 0 && slot < 2)
                    atomicMax(&pmax[slot * D + col], enc(v));   // LDS atomic
            }
        }
    }
#pragma unroll
    for (int f = 0; f < 6; ++f) {
        float r = psum[f];
        r += __shfl_xor(r, 16);
        r += __shfl_xor(r, 32);
        float r2 = pssq[f];
        r2 += __shfl_xor(r2, 16);
        r2 += __shfl_xor(r2, 32);
        if (lane < 16) {
            sr1[wv][f * 16 + lane] = r;
            sr2[wv][f * 16 + lane] = r2;
        }
    }
    __syncthreads();
    int t = wv * 64 + lane;
    if (t < D) {
        atomicAdd(&ssum[t], sr1[0][t] + sr1[1][t] + sr1[2][t] + sr1[3][t]);
    } else if (t < 2 * D) {
        int u = t - D;
        atomicAdd(&sssq[u], sr2[0][u] + sr2[1][u] + sr2[2][u] + sr2[3][u]);
    }
    if (t < 2 * D) {
        int sl = t / D, c = t % D;
        int gg = g0 + sl;
        if (gg < N_GRAPHS && pmax[t] != 0u)
            atomicMax(&poolu[gg * D + c], pmax[t]);
    }
}

// ---------------- head GEMMs: decode raw pooled max, apply prelu(bn2(.)) for l>=1 ----
__global__ void k_heads(const unsigned* __restrict__ pooledu, const float* __restrict__ stats,
                        const float* __restrict__ bng, const float* __restrict__ bnb,
                        const float* __restrict__ pa, const float* __restrict__ W,
                        const float* __restrict__ B, float* __restrict__ out) {
    __shared__ float pv[D];
    int b = blockIdx.x;
    int l = b >> 6;
    int g = b & 63;
    int d = threadIdx.x;
    if (d < D) {
        float m = dec(pooledu[(size_t)(l * N_GRAPHS + g) * D + d]);
        if (l > 0) {
            int gl = l - 1;
            const float* st = stats + (gl * 2 + 1) * 2 * D;
            float mean = st[d] * (1.0f / N_NODES);
            float var = st[D + d] * (1.0f / N_NODES) - mean * mean;
            float inv = rsqrtf(var + BN_EPS);
            float s = bng[gl * D + d] * inv;
            float t = bnb[gl * D + d] - mean * s;
            float v = m * s + t;
            m = (v >= 0.0f) ? v : pa[0] * v;
        }
        pv[d] = m;
    }
    __syncthreads();
    if (d >= D) return;
    const float* w = W + (size_t)l * D * D;
    float acc = B[l * D + d];
    for (int k = 0; k < D; ++k) acc += pv[k] * w[k * D + d];
    out[g * (5 * D) + d * 5 + l] = acc;
}

extern "C" void kernel_launch(void* const* d_in, const int* in_sizes, int n_in,
                              void* d_out, int out_size, void* d_ws, size_t ws_size,
                              hipStream_t stream) {
    const float* h     = (const float*)d_in[0];
    const float* gW1   = (const float*)d_in[1];
    const float* gb1   = (const float*)d_in[2];
    const float* bn1g  = (const float*)d_in[3];
    const float* bn1b  = (const float*)d_in[4];
    const float* gW2   = (const float*)d_in[5];
    const float* gb2   = (const float*)d_in[6];
    const float* bng   = (const float*)d_in[7];
    const float* bnb   = (const float*)d_in[8];
    const float* prelu = (const float*)d_in[9];
    const float* linW  = (const float*)d_in[10];
    const float* linb  = (const float*)d_in[11];
    const int*   srcv  = (const int*)d_in[12];
    const int*   dstv  = (const int*)d_in[13];
    float* out = (float*)d_out;

    char* base = (char*)d_ws;
    size_t off = 0;
    auto carve = [&](size_t bytes) -> void* {
        void* p = base + off;
        off += (bytes + 255) & ~(size_t)255;
        return p;
    };
    const size_t HB = (size_t)N_NODES * D;
    bf16* hb0   = (bf16*)carve((HB + D) * 2);   // h'_0 + phantom zero row (SENT)
    bf16* hb1   = (bf16*)carve((HB + D) * 2);   // h'_l for l>=1 + phantom zero row
    bf16* zb    = (bf16*)carve(HB * 2);         // z1
    bf16* ab    = (bf16*)carve(HB * 2);         // raw z2
    bf16* wf    = (bf16*)carve(8 * D * D * 2);
    float* stats = (float*)carve(N_GIN * 2 * 2 * D * 4);
    int* cnt    = (int*)carve((size_t)N_NODES * 4);              // compact degrees
    u16* ell    = (u16*)carve((size_t)N_NODES * ELLCAP * 2);     // ELL adjacency
    u32* eo     = (u32*)carve((size_t)N_EDGES * 4);              // bucket-sorted edges
    u16* offs   = (u16*)carve((size_t)(NBUCK + 1) * P1_BLOCKS * 2);
    unsigned* pooledu = (unsigned*)carve(5 * N_GRAPHS * D * 4);

    k_prolog<<<2472, 256, 0, stream>>>(h, hb0, hb1, gW1, gW2, wf, stats, pooledu);
    k_part_pool<<<P1_BLOCKS + N_GRAPHS * PCH / 16, 256, 0, stream>>>(
        srcv, dstv, eo, offs, hb0, pooledu);
    k_ell_build<<<NBUCK, 256, 0, stream>>>(eo, offs, ell, cnt);

    const bf16* prev = hb0;
    for (int l = 0; l < N_GIN; ++l) {
        float* st1 = stats + (l * 2 + 0) * 2 * D;
        float* st2 = stats + (l * 2 + 1) * 2 * D;
        if (l > 0) {
            float* stp = stats + ((l - 1) * 2 + 1) * 2 * D;
            k_transform<<<2344, 256, 0, stream>>>(ab, stp, bng + (l - 1) * D,
                                                  bnb + (l - 1) * D, prelu, hb1);
            prev = hb1;
        }
        k_agg_gemm<<<GEMM_GRID, 256, 0, stream>>>(prev, cnt, ell, wf + l * D * D,
                                                  gb1 + l * D, zb, st1, st1 + D);
        k_gemm_fused<<<GEMM_GRID, 256, 0, stream>>>(zb, wf + (4 + l) * D * D, st1,
                                                    bn1g + l * D, bn1b + l * D,
                                                    gb2 + l * D, ab, st2, st2 + D,
                                                    pooledu + (size_t)(l + 1) * N_GRAPHS * D);
    }
    k_heads<<<5 * N_GRAPHS, 128, 0, stream>>>(pooledu, stats, bng, bnb, prelu,
                                              linW, linb, out);
}